// Round 6
// baseline (170.506 us; speedup 1.0000x reference)
//
#include <hip/hip_runtime.h>
#include <math.h>
#include <string.h>

#define NBATCH 16

typedef __attribute__((ext_vector_type(8))) short short8;
typedef __attribute__((ext_vector_type(4))) float floatx4;
typedef __fp16 half2v __attribute__((ext_vector_type(2)));
#define MFMA16(a, b, c) __builtin_amdgcn_mfma_f32_16x16x32_bf16(a, b, c, 0, 0, 0)

// hardware RNE bf16 conversion (1 VALU op per pair vs ~10 for manual RNE)
__device__ __forceinline__ unsigned int cvtpk(float a, float b) {
  unsigned int r;
  asm("v_cvt_pk_bf16_f32 %0, %1, %2" : "=v"(r) : "v"(a), "v"(b));
  return r;
}
__device__ __forceinline__ unsigned short f2bf(float f) {
  return (unsigned short)(cvtpk(f, 0.f) & 0xffffu);
}
__device__ __forceinline__ unsigned int packbf2(float a, float b) {
  return cvtpk(a, b);
}
__device__ __forceinline__ float bflo(unsigned int u) {
  return __uint_as_float(u << 16);
}
__device__ __forceinline__ float bfhi(unsigned int u) {
  return __uint_as_float(u & 0xffff0000u);
}
__device__ __forceinline__ float fast_tanh(float x) {
  float e = __expf(2.f * x);
  return 1.f - 2.f / (e + 1.f);
}

// ---------------------------------------------------------------------------
// prep: fragment-order (swizzled) B layouts -> every wave B-load is one
// coalesced 1KB global_load_dwordx4.
//  coefswz: frag = ((rd*2+kc)*2+wj)*4+u  (rd<16,kc<2,wj<2,u<4), lane l:
//           coef[oc=wj*64+u*16+lm][k=rd*64+kc*32+lq*8+j]
//  w1swz:   frag = off*8 + kc*4 + wn*2 + u  -> w1[oc=wn*32+u*16+lm][ic=kc*32+lq*8+j][off]
//  w2swz:   frag = off*12 + kc*6 + wn*3 + u -> w2[oc=wn*48+u*16+lm][ic=kc*32+lq*8+j][off]
// ---------------------------------------------------------------------------
__global__ void prep_weights(const float* __restrict__ w1,
                             const float* __restrict__ w2,
                             const float* __restrict__ coef,
                             unsigned short* __restrict__ w1swz,
                             unsigned short* __restrict__ w2swz,
                             unsigned short* __restrict__ coefswz) {
  int i = blockIdx.x * 256 + threadIdx.x;
  if (i < 131072) {
    int j = i & 7, f = i >> 3;
    int lane = f & 63;
    int u = (f >> 6) & 3;
    int wj = (f >> 8) & 1;
    int kc = (f >> 9) & 1;
    int rd = f >> 10;
    int lm = lane & 15, lq = lane >> 4;
    int oc = wj * 64 + u * 16 + lm;
    int k = rd * 64 + kc * 32 + lq * 8 + j;
    coefswz[i] = f2bf(coef[oc * 1024 + k]);
  }
  if (i < 36864) {
    int j = i & 7, f = i >> 3;
    int lane = f & 63;
    int u = (f >> 6) & 1;
    int wn = (f >> 7) & 1;
    int kc = (f >> 8) & 1;
    int off = f >> 9;
    int lm = lane & 15, lq = lane >> 4;
    int oc = wn * 32 + u * 16 + lm;
    int ic = kc * 32 + lq * 8 + j;
    w1swz[i] = f2bf(w1[(oc * 64 + ic) * 9 + off]);
  }
  if (i < 55296) {
    int j = i & 7, f = i >> 3;
    int lane = f & 63;
    int rem = f >> 6;
    int u = rem % 3;
    int rem2 = rem / 3;
    int wn = rem2 & 1;
    int kc = (rem2 >> 1) & 1;
    int off = rem2 >> 2;
    int lm = lane & 15, lq = lane >> 4;
    int oc = wn * 48 + u * 16 + lm;
    int ic = kc * 32 + lq * 8 + j;
    w2swz[i] = f2bf(w2[(oc * 64 + ic) * 9 + off]);
  }
}

// ---------------------------------------------------------------------------
// x (fp32 NCHW) -> xb (bf16 NHWC), via LDS transpose. Block = (n, y) row.
// ---------------------------------------------------------------------------
__global__ __launch_bounds__(256) void xb_prep(const float* __restrict__ x,
                                               unsigned short* __restrict__ xb) {
  __shared__ float tile[64][65];
  const int t = threadIdx.x;
  const int y = blockIdx.x, n = blockIdx.y;
  const float* xn = x + (size_t)n * 64 * 4096 + y * 64;
#pragma unroll
  for (int it = 0; it < 16; ++it) {
    int idx = it * 256 + t;
    int c = idx >> 6, xx = idx & 63;
    tile[c][xx] = xn[c * 4096 + xx];
  }
  __syncthreads();
  const int xx = t >> 2, cq = t & 3;
  unsigned short* dst = xb + ((size_t)n * 4096 + y * 64 + xx) * 64;
#pragma unroll
  for (int jj = 0; jj < 2; ++jj) {
    int ch0 = cq * 16 + jj * 8;
    unsigned int p[4];
#pragma unroll
    for (int e = 0; e < 4; ++e)
      p[e] = packbf2(tile[ch0 + e * 2][xx], tile[ch0 + e * 2 + 1][xx]);
    *(uint4*)&dst[ch0] = make_uint4(p[0], p[1], p[2], p[3]);
  }
}

// ---------------------------------------------------------------------------
// Fused conv1+BN+tanh -> h (LDS) -> conv2+BN+tanh -> bc (global NHWC bf16)
// v2: 8x8 bc tile, grid (64, 16) = 1024 blocks (4/CU). LDS 39.2 KB.
// x region 12x12, h region 10x10 (alloc 128 pos; pads never read).
// h outside the image is ZERO (conv2 zero-padding semantics).
// ---------------------------------------------------------------------------
__global__ __launch_bounds__(256) void fused_conv(
    const unsigned short* __restrict__ xb, const unsigned short* __restrict__ w1swz,
    const unsigned short* __restrict__ w2swz, const float* __restrict__ b1,
    const float* __restrict__ g1, const float* __restrict__ be1,
    const float* __restrict__ m1, const float* __restrict__ v1,
    const float* __restrict__ b2, const float* __restrict__ g2,
    const float* __restrict__ be2, const float* __restrict__ m2,
    const float* __restrict__ v2, unsigned short* __restrict__ bcg) {
  __shared__ unsigned short xls[144 * 72];  // [(xr*12+xc)][ic]
  __shared__ unsigned short hls[128 * 72];  // [hr*10+hc][oc], 100 used

  const int t = threadIdx.x;
  const int tile = blockIdx.x, n = blockIdx.y;
  const int x0 = (tile & 7) * 8, y0 = (tile >> 3) * 8;

  // stage x: rows y0-2..y0+9, cols x0-2..x0+9
  const unsigned short* xbn = xb + (size_t)n * 4096 * 64;
#pragma unroll
  for (int it = 0; it < 5; ++it) {
    int idx = it * 256 + t;  // 1152 total
    if (idx < 1152) {
      int pos = idx >> 3, u4 = idx & 7;
      int xr = pos / 12, xc = pos - xr * 12;
      int gy = y0 - 2 + xr, gx = x0 - 2 + xc;
      uint4 v = {0u, 0u, 0u, 0u};
      if ((unsigned)gy < 64u && (unsigned)gx < 64u)
        v = *(const uint4*)&xbn[((size_t)gy * 64 + gx) * 64 + u4 * 8];
      *(uint4*)&xls[pos * 72 + u4 * 8] = v;
    }
  }
  __syncthreads();

  const int lane = t & 63, w = t >> 6;
  const int wm = w & 1, wn = w >> 1;
  const int lm = lane & 15, lq = lane >> 4;

  // ---- phase 1: h = tanh(bn1(conv1(x))), M=128 (100 used), N=64, K=576 ----
  int abase[4];
#pragma unroll
  for (int i = 0; i < 4; ++i) {
    int px = (wm + 2 * i) * 16 + lm;
    if (px > 99) px = 99;
    int hr = px / 10, hc = px - hr * 10;
    abase[i] = (hr * 12 + hc) * 72 + lq * 8;
  }
  floatx4 acc[4][2];
#pragma unroll
  for (int i = 0; i < 4; ++i)
#pragma unroll
    for (int u = 0; u < 2; ++u) acc[i][u] = floatx4{0.f, 0.f, 0.f, 0.f};

#pragma unroll
  for (int step = 0; step < 18; ++step) {
    const int off = step >> 1, kc = step & 1;
    const int di = off / 3, dj = off % 3;
    short8 b[2];
#pragma unroll
    for (int u = 0; u < 2; ++u)
      b[u] = *(const short8*)&w1swz[(off * 512 + kc * 256 + wn * 128 + u * 64 +
                                     lane) * 8];
#pragma unroll
    for (int i = 0; i < 4; ++i) {
      short8 a = *(const short8*)&xls[abase[i] + (di * 12 + dj) * 72 + kc * 32];
      acc[i][0] = MFMA16(a, b[0], acc[i][0]);
      acc[i][1] = MFMA16(a, b[1], acc[i][1]);
    }
  }
  {
    float sc[2], sh[2];
#pragma unroll
    for (int u = 0; u < 2; ++u) {
      int oc = wn * 32 + u * 16 + lm;
      sc[u] = g1[oc] * rsqrtf(v1[oc] + 1e-5f);
      sh[u] = (b1[oc] - m1[oc]) * sc[u] + be1[oc];
    }
#pragma unroll
    for (int i = 0; i < 4; ++i) {
      int px0 = (wm + 2 * i) * 16 + lq * 4;
#pragma unroll
      for (int u = 0; u < 2; ++u) {
        int oc = wn * 32 + u * 16 + lm;
#pragma unroll
        for (int r = 0; r < 4; ++r) {
          int px = px0 + r;
          if (px < 100) {
            int hr = px / 10, hc = px - hr * 10;
            int gy = y0 - 1 + hr, gx = x0 - 1 + hc;
            bool valid = ((unsigned)gy < 64u) && ((unsigned)gx < 64u);
            float val = valid ? fast_tanh(acc[i][u][r] * sc[u] + sh[u]) : 0.f;
            hls[px * 72 + oc] = f2bf(val);
          }
        }
      }
    }
  }
  __syncthreads();

  // ---- phase 2: bc = tanh(bn2(conv2(h))), M=64, N=96, K=576 ----
  int hbase[2];
#pragma unroll
  for (int s = 0; s < 2; ++s) {
    int opx = (wm + 2 * s) * 16 + lm;
    int yl = opx >> 3, xl = opx & 7;
    hbase[s] = (yl * 10 + xl) * 72 + lq * 8;
  }
  floatx4 acc2[2][3];
#pragma unroll
  for (int s = 0; s < 2; ++s)
#pragma unroll
    for (int u = 0; u < 3; ++u) acc2[s][u] = floatx4{0.f, 0.f, 0.f, 0.f};

#pragma unroll
  for (int step = 0; step < 18; ++step) {
    const int off = step >> 1, kc = step & 1;
    const int di = off / 3, dj = off % 3;
    short8 b[3];
#pragma unroll
    for (int u = 0; u < 3; ++u)
      b[u] = *(const short8*)&w2swz[(off * 768 + kc * 384 + wn * 192 + u * 64 +
                                     lane) * 8];
#pragma unroll
    for (int s = 0; s < 2; ++s) {
      short8 a = *(const short8*)&hls[hbase[s] + (di * 10 + dj) * 72 + kc * 32];
      acc2[s][0] = MFMA16(a, b[0], acc2[s][0]);
      acc2[s][1] = MFMA16(a, b[1], acc2[s][1]);
      acc2[s][2] = MFMA16(a, b[2], acc2[s][2]);
    }
  }
  {
    float sc[3], sh[3];
#pragma unroll
    for (int u = 0; u < 3; ++u) {
      int oc = wn * 48 + u * 16 + lm;
      sc[u] = g2[oc] * rsqrtf(v2[oc] + 1e-5f);
      sh[u] = (b2[oc] - m2[oc]) * sc[u] + be2[oc];
    }
    unsigned short* bcn = bcg + (size_t)n * 4096 * 96;
#pragma unroll
    for (int s = 0; s < 2; ++s) {
      int opx0 = (wm + 2 * s) * 16 + lq * 4;
#pragma unroll
      for (int u = 0; u < 3; ++u) {
        int oc = wn * 48 + u * 16 + lm;
#pragma unroll
        for (int r = 0; r < 4; ++r) {
          int opx = opx0 + r;
          int y = y0 + (opx >> 3), xx = x0 + (opx & 7);
          bcn[((size_t)y * 64 + xx) * 96 + oc] =
              f2bf(fast_tanh(acc2[s][u][r] * sc[u] + sh[u]));
        }
      }
    }
  }
}

// ---------------------------------------------------------------------------
// adconv v9: KILL THE SERIAL B-LOAD CHAIN. R5 post-mortem arithmetic: block
// wall-time ~126k cyc but per-block work only ~11k cyc; the gap matches 16
// B-frag loads/rd serialized at ~200cyc L2 latency (VGPR_Count=76 proves the
// compiler could NOT keep 16 short8 frags (64 VGPR) in flight -> emitted
// load;wait;MFMA;... serially). v8's low-reg "win" was the cause.
// v9 (same 64px tile, wave-private, barrier-free):
//  - __launch_bounds__(256,2): cap 256, compiler free, no forced spill.
//  - All 16 B-loads batch-issued at rd-loop top; build(rd+1) VALU (~420cyc)
//    runs between issue and MFMA consumption -> L2 latency fully hidden.
//  - at hoisted to f32 atf[9][4] (kills 54 unpack ops/rd; regs available).
// Expected: VGPR ~180-230 (the signature), dur 52.6 -> 25-35us. Occupancy
// drops to ~2 waves/SIMD -- intended: ILP replaces TLP for this stall.
// ---------------------------------------------------------------------------
__global__ __launch_bounds__(256, 2) void adconv_final(
    const unsigned short* __restrict__ xb, const unsigned short* __restrict__ bc,
    const float* __restrict__ bases, const unsigned short* __restrict__ coefswz,
    float* __restrict__ out) {
  __shared__ unsigned short xs[100 * 72];  // [(prow)*10 + qcol][c] 14.4 KB
  __shared__ unsigned short As[4 * 1024];  // per-wave [16px][64K] 8 KB

  const int t = threadIdx.x;
  const int tile = blockIdx.x, n = blockIdx.y;
  const int q0 = (tile & 7) * 8, p0 = (tile >> 3) * 8;

  float bs[54];
#pragma unroll
  for (int i = 0; i < 54; ++i) bs[i] = bases[i];

  // stage xs[pos][c]: rows p0-1..p0+8 (10), cols q0-1..q0+8 (10)
  const unsigned short* xbn = xb + (size_t)n * 4096 * 64;
#pragma unroll
  for (int it = 0; it < 4; ++it) {
    int idx = it * 256 + t;  // 800 total (100 pos x 8 uint4)
    if (idx < 800) {
      int pos = idx >> 3, u4 = idx & 7;
      int row = pos / 10, col = pos - row * 10;
      int gp = p0 - 1 + row, gq = q0 - 1 + col;
      uint4 v = {0u, 0u, 0u, 0u};
      if ((unsigned)gp < 64u && (unsigned)gq < 64u)
        v = *(const uint4*)&xbn[((size_t)gp * 64 + gq) * 64 + u4 * 8];
      *(uint4*)&xs[pos * 72 + u4 * 8] = v;
    }
  }

  const int lane = t & 63, w = t >> 6;
  const int lm = lane & 15, lq = lane >> 4;

  // builder role: 4 threads/px, wave-aligned (wave w builds px w*16..+15)
  const int pxl_b = lane >> 2, fh4 = lane & 3;  // local px, f-quarter
  const int px_b = w * 16 + pxl_b;
  const int qx_b = px_b >> 3, py_b = px_b & 7;

  // atoms[k][j] for f = fh4*4 + j (j<4), held UNPACKED in f32 (36 VGPRs):
  // avoids per-build re-unpacking (v8 cost ~54 ops/rd re-cvt'ing f16)
  float atf[9][4];
  {
    const unsigned short* bp =
        bc + ((size_t)n * 4096 + (q0 + qx_b) * 64 + (p0 + py_b)) * 96 + fh4 * 24;
    float bcv[24];
#pragma unroll
    for (int m = 0; m < 3; ++m) {
      uint4 v = *(const uint4*)(bp + m * 8);
      unsigned int uu[4] = {v.x, v.y, v.z, v.w};
#pragma unroll
      for (int e = 0; e < 4; ++e) {
        bcv[m * 8 + e * 2] = bflo(uu[e]);
        bcv[m * 8 + e * 2 + 1] = bfhi(uu[e]);
      }
    }
#pragma unroll
    for (int j = 0; j < 4; ++j)
#pragma unroll
      for (int k = 0; k < 9; ++k) {
        float s0 = 0.f;
#pragma unroll
        for (int tt = 0; tt < 6; ++tt)
          s0 = fmaf(bcv[j * 6 + tt], bs[tt * 9 + k], s0);
        atf[k][j] = s0;
      }
  }

  int pa[9];
#pragma unroll
  for (int i = 0; i < 3; ++i)
#pragma unroll
    for (int j = 0; j < 3; ++j)
      pa[i * 3 + j] = ((py_b + i) * 10 + qx_b + j) * 72;

  floatx4 acc[2][4];  // [wj][u]: full N=128 per wave
#pragma unroll
  for (int wj = 0; wj < 2; ++wj)
#pragma unroll
    for (int u = 0; u < 4; ++u) acc[wj][u] = floatx4{0.f, 0.f, 0.f, 0.f};

  unsigned short* Asw = &As[w * 1024];  // wave-private single buffer

  uint2 qv[9];
  auto qload = [&](int rd) {
    const int coff = rd * 4;
#pragma unroll
    for (int p = 0; p < 9; ++p) qv[p] = *(const uint2*)&xs[pa[p] + coff];
  };
  // build K-chunk (4 c, 4 f -> 16 K-elems per builder) into wave-private buf.
  auto build = [&]() {
    float a[4][4];
    {  // p = 0: mul (no zero-init pass)
      float c0 = bflo(qv[0].x), c1 = bfhi(qv[0].x);
      float c2 = bflo(qv[0].y), c3 = bfhi(qv[0].y);
#pragma unroll
      for (int j = 0; j < 4; ++j) {
        float av = atf[0][j];
        a[0][j] = c0 * av;
        a[1][j] = c1 * av;
        a[2][j] = c2 * av;
        a[3][j] = c3 * av;
      }
    }
#pragma unroll
    for (int p = 1; p < 9; ++p) {
      float c0 = bflo(qv[p].x), c1 = bfhi(qv[p].x);
      float c2 = bflo(qv[p].y), c3 = bfhi(qv[p].y);
#pragma unroll
      for (int j = 0; j < 4; ++j) {
        float av = atf[p][j];
        a[0][j] = fmaf(c0, av, a[0][j]);
        a[1][j] = fmaf(c1, av, a[1][j]);
        a[2][j] = fmaf(c2, av, a[2][j]);
        a[3][j] = fmaf(c3, av, a[3][j]);
      }
    }
#pragma unroll
    for (int cc = 0; cc < 4; ++cc) {
      int g = (cc * 4 + fh4) ^ ((pxl_b & 7) << 1);
      uint2 val;
      val.x = cvtpk(a[cc][0], a[cc][1]);
      val.y = cvtpk(a[cc][2], a[cc][3]);
      *(uint2*)&Asw[pxl_b * 64 + g * 4] = val;
    }
  };

  __syncthreads();  // xs staged (the only block-wide barrier)
  qload(0);
  build();

  for (int rd = 0; rd < 16; ++rd) {
    // 1) batch-issue ALL 16 B-frag loads for this rd (64 VGPRs in flight);
    //    their ~200cyc L2 latency is covered by build() below.
    short8 Bf[2][2][4];
#pragma unroll
    for (int kc = 0; kc < 2; ++kc)
#pragma unroll
      for (int wj = 0; wj < 2; ++wj)
#pragma unroll
        for (int u = 0; u < 4; ++u) {
          int frag = ((rd * 2 + kc) * 2 + wj) * 4 + u;
          Bf[kc][wj][u] =
              *(const short8*)(coefswz + ((size_t)frag * 64 + lane) * 8);
        }
    // 2) A frags for rd (ds_read precedes build()'s aliasing ds_write in
    //    program order; per-wave DS is in-order -> WAR-safe, no barrier)
    short8 Af[2];
#pragma unroll
    for (int kc = 0; kc < 2; ++kc) {
      int u16 = (kc * 4 + lq) ^ (lm & 7);
      Af[kc] = *(const short8*)&Asw[lm * 64 + u16 * 8];
    }
    // 3) next chunk build: ~420 VALU cycles hiding the B-load latency
    if (rd < 15) {
      qload(rd + 1);
      build();
    }
    // 4) consume: 16 MFMAs, operands all resident
    __builtin_amdgcn_s_setprio(1);
#pragma unroll
    for (int kc = 0; kc < 2; ++kc)
#pragma unroll
      for (int wj = 0; wj < 2; ++wj)
#pragma unroll
        for (int u = 0; u < 4; ++u)
          acc[wj][u] = MFMA16(Af[kc], Bf[kc][wj][u], acc[wj][u]);
    __builtin_amdgcn_s_setprio(0);
  }

  // epilogue: direct float4 stores (C/D reg-run contiguous along p)
  float* outn = out + (size_t)n * 128 * 4096;
#pragma unroll
  for (int wj = 0; wj < 2; ++wj)
#pragma unroll
    for (int u = 0; u < 4; ++u) {
      int oc = wj * 64 + u * 16 + lm;
      int gpx = w * 16 + lq * 4;  // tile-local px of acc run
      int qx = gpx >> 3, py0 = gpx & 7;
      *(float4*)&outn[((size_t)oc * 64 + q0 + qx) * 64 + p0 + py0] =
          make_float4(acc[wj][u][0], acc[wj][u][1], acc[wj][u][2],
                      acc[wj][u][3]);
    }
}

// ---------------------------------------------------------------------------
extern "C" void kernel_launch(void* const* d_in, const int* in_sizes, int n_in,
                              void* d_out, int out_size, void* d_ws,
                              size_t ws_size, hipStream_t stream) {
  const float* x = (const float*)d_in[0];
  const float* conv1_w = (const float*)d_in[1];
  const float* conv1_b = (const float*)d_in[2];
  const float* bn1_g = (const float*)d_in[3];
  const float* bn1_b = (const float*)d_in[4];
  const float* bn1_m = (const float*)d_in[5];
  const float* bn1_v = (const float*)d_in[6];
  const float* conv2_w = (const float*)d_in[7];
  const float* conv2_b = (const float*)d_in[8];
  const float* bn2_g = (const float*)d_in[9];
  const float* bn2_b = (const float*)d_in[10];
  const float* bn2_m = (const float*)d_in[11];
  const float* bn2_v = (const float*)d_in[12];
  const float* bases = (const float*)d_in[13];
  const float* coef = (const float*)d_in[14];
  float* out = (float*)d_out;

  char* ws = (char*)d_ws;
  unsigned short* xbuf = (unsigned short*)(ws);             // 8,388,608 B
  unsigned short* bcb = (unsigned short*)(ws + 8388608);    // 12,582,912 B
  unsigned short* w1swz = (unsigned short*)(ws + 20971520); // 73,728 B
  unsigned short* w2swz = (unsigned short*)(ws + 21045248); // 110,592 B
  unsigned short* coefswz = (unsigned short*)(ws + 21155840); // 262,144 B

  prep_weights<<<512, 256, 0, stream>>>(conv1_w, conv2_w, coef, w1swz, w2swz,
                                        coefswz);
  xb_prep<<<dim3(64, NBATCH), 256, 0, stream>>>(x, xbuf);
  fused_conv<<<dim3(64, NBATCH), 256, 0, stream>>>(
      xbuf, w1swz, w2swz, conv1_b, bn1_g, bn1_b, bn1_m, bn1_v, conv2_b, bn2_g,
      bn2_b, bn2_m, bn2_v, bcb);
  adconv_final<<<dim3(64, NBATCH), 256, 0, stream>>>(xbuf, bcb, bases, coefswz,
                                                     out);
}

// Round 7
// 165.732 us; speedup vs baseline: 1.0288x; 1.0288x over previous
//
#include <hip/hip_runtime.h>
#include <math.h>
#include <string.h>

#define NBATCH 16

typedef __attribute__((ext_vector_type(8))) short short8;
typedef __attribute__((ext_vector_type(4))) float floatx4;
#define MFMA16(a, b, c) __builtin_amdgcn_mfma_f32_16x16x32_bf16(a, b, c, 0, 0, 0)

// hardware RNE bf16 conversion (1 VALU op per pair vs ~10 for manual RNE)
__device__ __forceinline__ unsigned int cvtpk(float a, float b) {
  unsigned int r;
  asm("v_cvt_pk_bf16_f32 %0, %1, %2" : "=v"(r) : "v"(a), "v"(b));
  return r;
}
__device__ __forceinline__ unsigned short f2bf(float f) {
  return (unsigned short)(cvtpk(f, 0.f) & 0xffffu);
}
__device__ __forceinline__ unsigned int packbf2(float a, float b) {
  return cvtpk(a, b);
}
__device__ __forceinline__ float bflo(unsigned int u) {
  return __uint_as_float(u << 16);
}
__device__ __forceinline__ float bfhi(unsigned int u) {
  return __uint_as_float(u & 0xffff0000u);
}
__device__ __forceinline__ float fast_tanh(float x) {
  float e = __expf(2.f * x);
  return 1.f - 2.f / (e + 1.f);
}

// ---------------------------------------------------------------------------
// prep_all: merged xb_prep (blockIdx.x < 64) + prep_weights (blockIdx.x >= 64)
// -> one launch instead of two. Branch is block-uniform.
//  xb: x (fp32 NCHW) -> xb (bf16 NHWC) via LDS transpose, block = (n, y) row.
//  weights: fragment-order (swizzled) B layouts; every wave B-load in the
//  consumers is one coalesced 1KB global_load_dwordx4.
//   coefswz: frag = ((rd*2+kc)*2+wj)*4+u -> coef[oc=wj*64+u*16+lm][k=rd*64+kc*32+lq*8+j]
//   w1swz:   frag = off*8 + kc*4 + wn*2 + u  -> w1[oc=wn*32+u*16+lm][ic=kc*32+lq*8+j][off]
//   w2swz:   frag = off*12 + kc*6 + wn*3 + u -> w2[oc=wn*48+u*16+lm][ic=kc*32+lq*8+j][off]
// ---------------------------------------------------------------------------
__global__ __launch_bounds__(256) void prep_all(
    const float* __restrict__ x, unsigned short* __restrict__ xb,
    const float* __restrict__ w1, const float* __restrict__ w2,
    const float* __restrict__ coef, unsigned short* __restrict__ w1swz,
    unsigned short* __restrict__ w2swz, unsigned short* __restrict__ coefswz) {
  __shared__ float tile[64][65];
  const int t = threadIdx.x;
  if (blockIdx.x < 64) {
    const int y = blockIdx.x, n = blockIdx.y;
    const float* xn = x + (size_t)n * 64 * 4096 + y * 64;
#pragma unroll
    for (int it = 0; it < 16; ++it) {
      int idx = it * 256 + t;
      int c = idx >> 6, xx = idx & 63;
      tile[c][xx] = xn[c * 4096 + xx];
    }
    __syncthreads();
    const int xx = t >> 2, cq = t & 3;
    unsigned short* dst = xb + ((size_t)n * 4096 + y * 64 + xx) * 64;
#pragma unroll
    for (int jj = 0; jj < 2; ++jj) {
      int ch0 = cq * 16 + jj * 8;
      unsigned int p[4];
#pragma unroll
      for (int e = 0; e < 4; ++e)
        p[e] = packbf2(tile[ch0 + e * 2][xx], tile[ch0 + e * 2 + 1][xx]);
      *(uint4*)&dst[ch0] = make_uint4(p[0], p[1], p[2], p[3]);
    }
    return;
  }
  // weights part: reproduce old 512-block x 256-thread index space
  int i = ((blockIdx.x - 64) * NBATCH + blockIdx.y) * 256 + t;
  if (i < 131072) {
    int j = i & 7, f = i >> 3;
    int lane = f & 63;
    int u = (f >> 6) & 3;
    int wj = (f >> 8) & 1;
    int kc = (f >> 9) & 1;
    int rd = f >> 10;
    int lm = lane & 15, lq = lane >> 4;
    int oc = wj * 64 + u * 16 + lm;
    int k = rd * 64 + kc * 32 + lq * 8 + j;
    coefswz[i] = f2bf(coef[oc * 1024 + k]);
  }
  if (i < 36864) {
    int j = i & 7, f = i >> 3;
    int lane = f & 63;
    int u = (f >> 6) & 1;
    int wn = (f >> 7) & 1;
    int kc = (f >> 8) & 1;
    int off = f >> 9;
    int lm = lane & 15, lq = lane >> 4;
    int oc = wn * 32 + u * 16 + lm;
    int ic = kc * 32 + lq * 8 + j;
    w1swz[i] = f2bf(w1[(oc * 64 + ic) * 9 + off]);
  }
  if (i < 55296) {
    int j = i & 7, f = i >> 3;
    int lane = f & 63;
    int rem = f >> 6;
    int u = rem % 3;
    int rem2 = rem / 3;
    int wn = rem2 & 1;
    int kc = (rem2 >> 1) & 1;
    int off = rem2 >> 2;
    int lm = lane & 15, lq = lane >> 4;
    int oc = wn * 48 + u * 16 + lm;
    int ic = kc * 32 + lq * 8 + j;
    w2swz[i] = f2bf(w2[(oc * 64 + ic) * 9 + off]);
  }
}

// ---------------------------------------------------------------------------
// Fused conv1+BN+tanh -> h (LDS) -> conv2+BN+tanh -> bc (global NHWC bf16)
// 8x8 bc tile, grid (64, 16) = 1024 blocks (4/CU). LDS 39.2 KB.
// ---------------------------------------------------------------------------
__global__ __launch_bounds__(256) void fused_conv(
    const unsigned short* __restrict__ xb, const unsigned short* __restrict__ w1swz,
    const unsigned short* __restrict__ w2swz, const float* __restrict__ b1,
    const float* __restrict__ g1, const float* __restrict__ be1,
    const float* __restrict__ m1, const float* __restrict__ v1,
    const float* __restrict__ b2, const float* __restrict__ g2,
    const float* __restrict__ be2, const float* __restrict__ m2,
    const float* __restrict__ v2, unsigned short* __restrict__ bcg) {
  __shared__ unsigned short xls[144 * 72];  // [(xr*12+xc)][ic]
  __shared__ unsigned short hls[128 * 72];  // [hr*10+hc][oc], 100 used

  const int t = threadIdx.x;
  const int tile = blockIdx.x, n = blockIdx.y;
  const int x0 = (tile & 7) * 8, y0 = (tile >> 3) * 8;

  // stage x: rows y0-2..y0+9, cols x0-2..x0+9
  const unsigned short* xbn = xb + (size_t)n * 4096 * 64;
#pragma unroll
  for (int it = 0; it < 5; ++it) {
    int idx = it * 256 + t;  // 1152 total
    if (idx < 1152) {
      int pos = idx >> 3, u4 = idx & 7;
      int xr = pos / 12, xc = pos - xr * 12;
      int gy = y0 - 2 + xr, gx = x0 - 2 + xc;
      uint4 v = {0u, 0u, 0u, 0u};
      if ((unsigned)gy < 64u && (unsigned)gx < 64u)
        v = *(const uint4*)&xbn[((size_t)gy * 64 + gx) * 64 + u4 * 8];
      *(uint4*)&xls[pos * 72 + u4 * 8] = v;
    }
  }
  __syncthreads();

  const int lane = t & 63, w = t >> 6;
  const int wm = w & 1, wn = w >> 1;
  const int lm = lane & 15, lq = lane >> 4;

  // ---- phase 1: h = tanh(bn1(conv1(x))), M=128 (100 used), N=64, K=576 ----
  int abase[4];
#pragma unroll
  for (int i = 0; i < 4; ++i) {
    int px = (wm + 2 * i) * 16 + lm;
    if (px > 99) px = 99;
    int hr = px / 10, hc = px - hr * 10;
    abase[i] = (hr * 12 + hc) * 72 + lq * 8;
  }
  floatx4 acc[4][2];
#pragma unroll
  for (int i = 0; i < 4; ++i)
#pragma unroll
    for (int u = 0; u < 2; ++u) acc[i][u] = floatx4{0.f, 0.f, 0.f, 0.f};

#pragma unroll
  for (int step = 0; step < 18; ++step) {
    const int off = step >> 1, kc = step & 1;
    const int di = off / 3, dj = off % 3;
    short8 b[2];
#pragma unroll
    for (int u = 0; u < 2; ++u)
      b[u] = *(const short8*)&w1swz[(off * 512 + kc * 256 + wn * 128 + u * 64 +
                                     lane) * 8];
#pragma unroll
    for (int i = 0; i < 4; ++i) {
      short8 a = *(const short8*)&xls[abase[i] + (di * 12 + dj) * 72 + kc * 32];
      acc[i][0] = MFMA16(a, b[0], acc[i][0]);
      acc[i][1] = MFMA16(a, b[1], acc[i][1]);
    }
  }
  {
    float sc[2], sh[2];
#pragma unroll
    for (int u = 0; u < 2; ++u) {
      int oc = wn * 32 + u * 16 + lm;
      sc[u] = g1[oc] * rsqrtf(v1[oc] + 1e-5f);
      sh[u] = (b1[oc] - m1[oc]) * sc[u] + be1[oc];
    }
#pragma unroll
    for (int i = 0; i < 4; ++i) {
      int px0 = (wm + 2 * i) * 16 + lq * 4;
#pragma unroll
      for (int u = 0; u < 2; ++u) {
        int oc = wn * 32 + u * 16 + lm;
#pragma unroll
        for (int r = 0; r < 4; ++r) {
          int px = px0 + r;
          if (px < 100) {
            int hr = px / 10, hc = px - hr * 10;
            int gy = y0 - 1 + hr, gx = x0 - 1 + hc;
            bool valid = ((unsigned)gy < 64u) && ((unsigned)gx < 64u);
            float val = valid ? fast_tanh(acc[i][u][r] * sc[u] + sh[u]) : 0.f;
            hls[px * 72 + oc] = f2bf(val);
          }
        }
      }
    }
  }
  __syncthreads();

  // ---- phase 2: bc = tanh(bn2(conv2(h))), M=64, N=96, K=576 ----
  int hbase[2];
#pragma unroll
  for (int s = 0; s < 2; ++s) {
    int opx = (wm + 2 * s) * 16 + lm;
    int yl = opx >> 3, xl = opx & 7;
    hbase[s] = (yl * 10 + xl) * 72 + lq * 8;
  }
  floatx4 acc2[2][3];
#pragma unroll
  for (int s = 0; s < 2; ++s)
#pragma unroll
    for (int u = 0; u < 3; ++u) acc2[s][u] = floatx4{0.f, 0.f, 0.f, 0.f};

#pragma unroll
  for (int step = 0; step < 18; ++step) {
    const int off = step >> 1, kc = step & 1;
    const int di = off / 3, dj = off % 3;
    short8 b[3];
#pragma unroll
    for (int u = 0; u < 3; ++u)
      b[u] = *(const short8*)&w2swz[(off * 768 + kc * 384 + wn * 192 + u * 64 +
                                     lane) * 8];
#pragma unroll
    for (int s = 0; s < 2; ++s) {
      short8 a = *(const short8*)&hls[hbase[s] + (di * 10 + dj) * 72 + kc * 32];
      acc2[s][0] = MFMA16(a, b[0], acc2[s][0]);
      acc2[s][1] = MFMA16(a, b[1], acc2[s][1]);
      acc2[s][2] = MFMA16(a, b[2], acc2[s][2]);
    }
  }
  {
    float sc[3], sh[3];
#pragma unroll
    for (int u = 0; u < 3; ++u) {
      int oc = wn * 48 + u * 16 + lm;
      sc[u] = g2[oc] * rsqrtf(v2[oc] + 1e-5f);
      sh[u] = (b2[oc] - m2[oc]) * sc[u] + be2[oc];
    }
    unsigned short* bcn = bcg + (size_t)n * 4096 * 96;
#pragma unroll
    for (int s = 0; s < 2; ++s) {
      int opx0 = (wm + 2 * s) * 16 + lq * 4;
#pragma unroll
      for (int u = 0; u < 3; ++u) {
        int oc = wn * 48 + u * 16 + lm;
#pragma unroll
        for (int r = 0; r < 4; ++r) {
          int opx = opx0 + r;
          int y = y0 + (opx >> 3), xx = x0 + (opx & 7);
          bcn[((size_t)y * 64 + xx) * 96 + oc] =
              f2bf(fast_tanh(acc2[s][u][r] * sc[u] + sh[u]));
        }
      }
    }
  }
}

// ---------------------------------------------------------------------------
// adconv v10: FENCED B-PREFETCH + fp32 xs.
// R6 post-mortem: VGPR stayed 96 -> compiler SANK the batch-issued B-loads
// back to their uses (register minimization); the R5 serial-load theory was
// never actually tested. v10 forces it with a compiler memory fence
// (asm volatile "memory") after the 16-load block: memory ops cannot cross
// -> Bf held ~64 VGPRs across build(), L2 latency hidden under build VALU.
// Also: xs kept in fp32 (27.2 KB; +As 8 KB = 35.4 KB still 4 blocks/CU):
// qload = ds_read_b128, no bf16 unpack -> -36 VALU ops/rd (~19% of build).
// Gates: VGPR >= 160 (fence worked); WRITE_SIZE stays 32.8 MB (no spill).
// If VGPR high but dur flat -> latency theory dead; next: double-buffer As.
// ---------------------------------------------------------------------------
__global__ __launch_bounds__(256, 2) void adconv_final(
    const unsigned short* __restrict__ xb, const unsigned short* __restrict__ bc,
    const float* __restrict__ bases, const unsigned short* __restrict__ coefswz,
    float* __restrict__ out) {
  __shared__ float xs[100 * 68];           // [(prow)*10 + qcol][c] fp32, 27.2 KB
  __shared__ unsigned short As[4 * 1024];  // per-wave [16px][64K] bf16, 8 KB

  const int t = threadIdx.x;
  const int tile = blockIdx.x, n = blockIdx.y;
  const int q0 = (tile & 7) * 8, p0 = (tile >> 3) * 8;

  float bs[54];
#pragma unroll
  for (int i = 0; i < 54; ++i) bs[i] = bases[i];

  // stage xs[pos][c] in fp32: rows p0-1..p0+8 (10), cols q0-1..q0+8 (10)
  const unsigned short* xbn = xb + (size_t)n * 4096 * 64;
#pragma unroll
  for (int it = 0; it < 4; ++it) {
    int idx = it * 256 + t;  // 800 total (100 pos x 8 bf16-uint4 units)
    if (idx < 800) {
      int pos = idx >> 3, u4 = idx & 7;
      int row = pos / 10, col = pos - row * 10;
      int gp = p0 - 1 + row, gq = q0 - 1 + col;
      uint4 v = {0u, 0u, 0u, 0u};
      if ((unsigned)gp < 64u && (unsigned)gq < 64u)
        v = *(const uint4*)&xbn[((size_t)gp * 64 + gq) * 64 + u4 * 8];
      float* d = &xs[pos * 68 + u4 * 8];
      *(float4*)d = make_float4(bflo(v.x), bfhi(v.x), bflo(v.y), bfhi(v.y));
      *(float4*)(d + 4) =
          make_float4(bflo(v.z), bfhi(v.z), bflo(v.w), bfhi(v.w));
    }
  }

  const int lane = t & 63, w = t >> 6;
  const int lm = lane & 15, lq = lane >> 4;

  // builder role: 4 threads/px, wave-aligned (wave w builds px w*16..+15)
  const int pxl_b = lane >> 2, fh4 = lane & 3;  // local px, f-quarter
  const int px_b = w * 16 + pxl_b;
  const int qx_b = px_b >> 3, py_b = px_b & 7;

  // atoms[k][j] for f = fh4*4 + j (j<4), f32 (36 VGPRs)
  float atf[9][4];
  {
    const unsigned short* bp =
        bc + ((size_t)n * 4096 + (q0 + qx_b) * 64 + (p0 + py_b)) * 96 + fh4 * 24;
    float bcv[24];
#pragma unroll
    for (int m = 0; m < 3; ++m) {
      uint4 v = *(const uint4*)(bp + m * 8);
      unsigned int uu[4] = {v.x, v.y, v.z, v.w};
#pragma unroll
      for (int e = 0; e < 4; ++e) {
        bcv[m * 8 + e * 2] = bflo(uu[e]);
        bcv[m * 8 + e * 2 + 1] = bfhi(uu[e]);
      }
    }
#pragma unroll
    for (int j = 0; j < 4; ++j)
#pragma unroll
      for (int k = 0; k < 9; ++k) {
        float s0 = 0.f;
#pragma unroll
        for (int tt = 0; tt < 6; ++tt)
          s0 = fmaf(bcv[j * 6 + tt], bs[tt * 9 + k], s0);
        atf[k][j] = s0;
      }
  }

  int pa[9];
#pragma unroll
  for (int i = 0; i < 3; ++i)
#pragma unroll
    for (int j = 0; j < 3; ++j)
      pa[i * 3 + j] = ((py_b + i) * 10 + qx_b + j) * 68;

  floatx4 acc[2][4];  // [wj][u]: full N=128 per wave
#pragma unroll
  for (int wj = 0; wj < 2; ++wj)
#pragma unroll
    for (int u = 0; u < 4; ++u) acc[wj][u] = floatx4{0.f, 0.f, 0.f, 0.f};

  unsigned short* Asw = &As[w * 1024];  // wave-private single buffer

  float4 qv[9];
  auto qload = [&](int rd) {
    const int coff = rd * 4;
#pragma unroll
    for (int p = 0; p < 9; ++p) qv[p] = *(const float4*)&xs[pa[p] + coff];
  };
  // build K-chunk (4 c, 4 f -> 16 K-elems per builder) into wave-private buf.
  auto build = [&]() {
    float a[4][4];
    {  // p = 0: mul (no zero-init pass)
#pragma unroll
      for (int j = 0; j < 4; ++j) {
        float av = atf[0][j];
        a[0][j] = qv[0].x * av;
        a[1][j] = qv[0].y * av;
        a[2][j] = qv[0].z * av;
        a[3][j] = qv[0].w * av;
      }
    }
#pragma unroll
    for (int p = 1; p < 9; ++p) {
#pragma unroll
      for (int j = 0; j < 4; ++j) {
        float av = atf[p][j];
        a[0][j] = fmaf(qv[p].x, av, a[0][j]);
        a[1][j] = fmaf(qv[p].y, av, a[1][j]);
        a[2][j] = fmaf(qv[p].z, av, a[2][j]);
        a[3][j] = fmaf(qv[p].w, av, a[3][j]);
      }
    }
#pragma unroll
    for (int cc = 0; cc < 4; ++cc) {
      int g = (cc * 4 + fh4) ^ ((pxl_b & 7) << 1);
      uint2 val;
      val.x = cvtpk(a[cc][0], a[cc][1]);
      val.y = cvtpk(a[cc][2], a[cc][3]);
      *(uint2*)&Asw[pxl_b * 64 + g * 4] = val;
    }
  };

  __syncthreads();  // xs staged (the only block-wide barrier)
  qload(0);
  build();

  for (int rd = 0; rd < 16; ++rd) {
    // 1) batch-issue ALL 16 B-frag loads; the fence below PINS them here
    //    (memory ops cannot be reordered across it) so they stay in flight
    //    across build() instead of being sunk to the MFMAs.
    short8 Bf[2][2][4];
#pragma unroll
    for (int kc = 0; kc < 2; ++kc)
#pragma unroll
      for (int wj = 0; wj < 2; ++wj)
#pragma unroll
        for (int u = 0; u < 4; ++u) {
          int frag = ((rd * 2 + kc) * 2 + wj) * 4 + u;
          Bf[kc][wj][u] =
              *(const short8*)(coefswz + ((size_t)frag * 64 + lane) * 8);
        }
    asm volatile("" ::: "memory");  // scheduling fence: no load sinking
    // 2) A frags for rd (ds_read precedes build()'s aliasing ds_write in
    //    program order; per-wave DS is in-order -> WAR-safe, no barrier)
    short8 Af[2];
#pragma unroll
    for (int kc = 0; kc < 2; ++kc) {
      int u16 = (kc * 4 + lq) ^ (lm & 7);
      Af[kc] = *(const short8*)&Asw[lm * 64 + u16 * 8];
    }
    // 3) next chunk build: ~300 VALU cycles hiding the B-load latency
    if (rd < 15) {
      qload(rd + 1);
      build();
    }
    // 4) consume: 16 MFMAs, operands all resident
    __builtin_amdgcn_s_setprio(1);
#pragma unroll
    for (int kc = 0; kc < 2; ++kc)
#pragma unroll
      for (int wj = 0; wj < 2; ++wj)
#pragma unroll
        for (int u = 0; u < 4; ++u)
          acc[wj][u] = MFMA16(Af[kc], Bf[kc][wj][u], acc[wj][u]);
    __builtin_amdgcn_s_setprio(0);
  }

  // epilogue: direct float4 stores (C/D reg-run contiguous along p)
  float* outn = out + (size_t)n * 128 * 4096;
#pragma unroll
  for (int wj = 0; wj < 2; ++wj)
#pragma unroll
    for (int u = 0; u < 4; ++u) {
      int oc = wj * 64 + u * 16 + lm;
      int gpx = w * 16 + lq * 4;  // tile-local px of acc run
      int qx = gpx >> 3, py0 = gpx & 7;
      *(float4*)&outn[((size_t)oc * 64 + q0 + qx) * 64 + p0 + py0] =
          make_float4(acc[wj][u][0], acc[wj][u][1], acc[wj][u][2],
                      acc[wj][u][3]);
    }
}

// ---------------------------------------------------------------------------
extern "C" void kernel_launch(void* const* d_in, const int* in_sizes, int n_in,
                              void* d_out, int out_size, void* d_ws,
                              size_t ws_size, hipStream_t stream) {
  const float* x = (const float*)d_in[0];
  const float* conv1_w = (const float*)d_in[1];
  const float* conv1_b = (const float*)d_in[2];
  const float* bn1_g = (const float*)d_in[3];
  const float* bn1_b = (const float*)d_in[4];
  const float* bn1_m = (const float*)d_in[5];
  const float* bn1_v = (const float*)d_in[6];
  const float* conv2_w = (const float*)d_in[7];
  const float* conv2_b = (const float*)d_in[8];
  const float* bn2_g = (const float*)d_in[9];
  const float* bn2_b = (const float*)d_in[10];
  const float* bn2_m = (const float*)d_in[11];
  const float* bn2_v = (const float*)d_in[12];
  const float* bases = (const float*)d_in[13];
  const float* coef = (const float*)d_in[14];
  float* out = (float*)d_out;

  char* ws = (char*)d_ws;
  unsigned short* xbuf = (unsigned short*)(ws);             // 8,388,608 B
  unsigned short* bcb = (unsigned short*)(ws + 8388608);    // 12,582,912 B
  unsigned short* w1swz = (unsigned short*)(ws + 20971520); // 73,728 B
  unsigned short* w2swz = (unsigned short*)(ws + 21045248); // 110,592 B
  unsigned short* coefswz = (unsigned short*)(ws + 21155840); // 262,144 B

  prep_all<<<dim3(96, NBATCH), 256, 0, stream>>>(x, xbuf, conv1_w, conv2_w,
                                                 coef, w1swz, w2swz, coefswz);
  fused_conv<<<dim3(64, NBATCH), 256, 0, stream>>>(
      xbuf, w1swz, w2swz, conv1_b, bn1_g, bn1_b, bn1_m, bn1_v, conv2_b, bn2_g,
      bn2_b, bn2_m, bn2_v, bcb);
  adconv_final<<<dim3(64, NBATCH), 256, 0, stream>>>(xbuf, bcb, bases, coefswz,
                                                     out);
}

// Round 8
// 165.250 us; speedup vs baseline: 1.0318x; 1.0029x over previous
//
#include <hip/hip_runtime.h>
#include <math.h>
#include <string.h>

#define NBATCH 16

typedef __attribute__((ext_vector_type(8))) short short8;
typedef __attribute__((ext_vector_type(4))) float floatx4;
#define MFMA16(a, b, c) __builtin_amdgcn_mfma_f32_16x16x32_bf16(a, b, c, 0, 0, 0)

// hardware RNE bf16 conversion (1 VALU op per pair vs ~10 for manual RNE)
__device__ __forceinline__ unsigned int cvtpk(float a, float b) {
  unsigned int r;
  asm("v_cvt_pk_bf16_f32 %0, %1, %2" : "=v"(r) : "v"(a), "v"(b));
  return r;
}
__device__ __forceinline__ unsigned short f2bf(float f) {
  return (unsigned short)(cvtpk(f, 0.f) & 0xffffu);
}
__device__ __forceinline__ unsigned int packbf2(float a, float b) {
  return cvtpk(a, b);
}
__device__ __forceinline__ float bflo(unsigned int u) {
  return __uint_as_float(u << 16);
}
__device__ __forceinline__ float bfhi(unsigned int u) {
  return __uint_as_float(u & 0xffff0000u);
}
__device__ __forceinline__ float fast_tanh(float x) {
  float e = __expf(2.f * x);
  return 1.f - 2.f / (e + 1.f);
}

// ---------------------------------------------------------------------------
// prep_all: merged xb_prep (blockIdx.x < 64) + prep_weights (blockIdx.x >= 64)
// -> one launch instead of two. Branch is block-uniform.
//  xb: x (fp32 NCHW) -> xb (bf16 NHWC) via LDS transpose, block = (n, y) row.
//  weights: fragment-order (swizzled) B layouts; every wave B-load in the
//  consumers is one coalesced 1KB global_load_dwordx4.
//   coefswz: frag = ((rd*2+kc)*2+wj)*4+u -> coef[oc=wj*64+u*16+lm][k=rd*64+kc*32+lq*8+j]
//   w1swz:   frag = off*8 + kc*4 + wn*2 + u  -> w1[oc=wn*32+u*16+lm][ic=kc*32+lq*8+j][off]
//   w2swz:   frag = off*12 + kc*6 + wn*3 + u -> w2[oc=wn*48+u*16+lm][ic=kc*32+lq*8+j][off]
// ---------------------------------------------------------------------------
__global__ __launch_bounds__(256) void prep_all(
    const float* __restrict__ x, unsigned short* __restrict__ xb,
    const float* __restrict__ w1, const float* __restrict__ w2,
    const float* __restrict__ coef, unsigned short* __restrict__ w1swz,
    unsigned short* __restrict__ w2swz, unsigned short* __restrict__ coefswz) {
  __shared__ float tile[64][65];
  const int t = threadIdx.x;
  if (blockIdx.x < 64) {
    const int y = blockIdx.x, n = blockIdx.y;
    const float* xn = x + (size_t)n * 64 * 4096 + y * 64;
#pragma unroll
    for (int it = 0; it < 16; ++it) {
      int idx = it * 256 + t;
      int c = idx >> 6, xx = idx & 63;
      tile[c][xx] = xn[c * 4096 + xx];
    }
    __syncthreads();
    const int xx = t >> 2, cq = t & 3;
    unsigned short* dst = xb + ((size_t)n * 4096 + y * 64 + xx) * 64;
#pragma unroll
    for (int jj = 0; jj < 2; ++jj) {
      int ch0 = cq * 16 + jj * 8;
      unsigned int p[4];
#pragma unroll
      for (int e = 0; e < 4; ++e)
        p[e] = packbf2(tile[ch0 + e * 2][xx], tile[ch0 + e * 2 + 1][xx]);
      *(uint4*)&dst[ch0] = make_uint4(p[0], p[1], p[2], p[3]);
    }
    return;
  }
  // weights part: reproduce old 512-block x 256-thread index space
  int i = ((blockIdx.x - 64) * NBATCH + blockIdx.y) * 256 + t;
  if (i < 131072) {
    int j = i & 7, f = i >> 3;
    int lane = f & 63;
    int u = (f >> 6) & 3;
    int wj = (f >> 8) & 1;
    int kc = (f >> 9) & 1;
    int rd = f >> 10;
    int lm = lane & 15, lq = lane >> 4;
    int oc = wj * 64 + u * 16 + lm;
    int k = rd * 64 + kc * 32 + lq * 8 + j;
    coefswz[i] = f2bf(coef[oc * 1024 + k]);
  }
  if (i < 36864) {
    int j = i & 7, f = i >> 3;
    int lane = f & 63;
    int u = (f >> 6) & 1;
    int wn = (f >> 7) & 1;
    int kc = (f >> 8) & 1;
    int off = f >> 9;
    int lm = lane & 15, lq = lane >> 4;
    int oc = wn * 32 + u * 16 + lm;
    int ic = kc * 32 + lq * 8 + j;
    w1swz[i] = f2bf(w1[(oc * 64 + ic) * 9 + off]);
  }
  if (i < 55296) {
    int j = i & 7, f = i >> 3;
    int lane = f & 63;
    int rem = f >> 6;
    int u = rem % 3;
    int rem2 = rem / 3;
    int wn = rem2 & 1;
    int kc = (rem2 >> 1) & 1;
    int off = rem2 >> 2;
    int lm = lane & 15, lq = lane >> 4;
    int oc = wn * 48 + u * 16 + lm;
    int ic = kc * 32 + lq * 8 + j;
    w2swz[i] = f2bf(w2[(oc * 64 + ic) * 9 + off]);
  }
}

// ---------------------------------------------------------------------------
// Fused conv1+BN+tanh -> h (LDS) -> conv2+BN+tanh -> bc (global NHWC bf16)
// 8x8 bc tile, grid (64, 16) = 1024 blocks (4/CU). LDS 39.2 KB.
// ---------------------------------------------------------------------------
__global__ __launch_bounds__(256) void fused_conv(
    const unsigned short* __restrict__ xb, const unsigned short* __restrict__ w1swz,
    const unsigned short* __restrict__ w2swz, const float* __restrict__ b1,
    const float* __restrict__ g1, const float* __restrict__ be1,
    const float* __restrict__ m1, const float* __restrict__ v1,
    const float* __restrict__ b2, const float* __restrict__ g2,
    const float* __restrict__ be2, const float* __restrict__ m2,
    const float* __restrict__ v2, unsigned short* __restrict__ bcg) {
  __shared__ unsigned short xls[144 * 72];  // [(xr*12+xc)][ic]
  __shared__ unsigned short hls[128 * 72];  // [hr*10+hc][oc], 100 used

  const int t = threadIdx.x;
  const int tile = blockIdx.x, n = blockIdx.y;
  const int x0 = (tile & 7) * 8, y0 = (tile >> 3) * 8;

  // stage x: rows y0-2..y0+9, cols x0-2..x0+9
  const unsigned short* xbn = xb + (size_t)n * 4096 * 64;
#pragma unroll
  for (int it = 0; it < 5; ++it) {
    int idx = it * 256 + t;  // 1152 total
    if (idx < 1152) {
      int pos = idx >> 3, u4 = idx & 7;
      int xr = pos / 12, xc = pos - xr * 12;
      int gy = y0 - 2 + xr, gx = x0 - 2 + xc;
      uint4 v = {0u, 0u, 0u, 0u};
      if ((unsigned)gy < 64u && (unsigned)gx < 64u)
        v = *(const uint4*)&xbn[((size_t)gy * 64 + gx) * 64 + u4 * 8];
      *(uint4*)&xls[pos * 72 + u4 * 8] = v;
    }
  }
  __syncthreads();

  const int lane = t & 63, w = t >> 6;
  const int wm = w & 1, wn = w >> 1;
  const int lm = lane & 15, lq = lane >> 4;

  // ---- phase 1: h = tanh(bn1(conv1(x))), M=128 (100 used), N=64, K=576 ----
  int abase[4];
#pragma unroll
  for (int i = 0; i < 4; ++i) {
    int px = (wm + 2 * i) * 16 + lm;
    if (px > 99) px = 99;
    int hr = px / 10, hc = px - hr * 10;
    abase[i] = (hr * 12 + hc) * 72 + lq * 8;
  }
  floatx4 acc[4][2];
#pragma unroll
  for (int i = 0; i < 4; ++i)
#pragma unroll
    for (int u = 0; u < 2; ++u) acc[i][u] = floatx4{0.f, 0.f, 0.f, 0.f};

#pragma unroll
  for (int step = 0; step < 18; ++step) {
    const int off = step >> 1, kc = step & 1;
    const int di = off / 3, dj = off % 3;
    short8 b[2];
#pragma unroll
    for (int u = 0; u < 2; ++u)
      b[u] = *(const short8*)&w1swz[(off * 512 + kc * 256 + wn * 128 + u * 64 +
                                     lane) * 8];
#pragma unroll
    for (int i = 0; i < 4; ++i) {
      short8 a = *(const short8*)&xls[abase[i] + (di * 12 + dj) * 72 + kc * 32];
      acc[i][0] = MFMA16(a, b[0], acc[i][0]);
      acc[i][1] = MFMA16(a, b[1], acc[i][1]);
    }
  }
  {
    float sc[2], sh[2];
#pragma unroll
    for (int u = 0; u < 2; ++u) {
      int oc = wn * 32 + u * 16 + lm;
      sc[u] = g1[oc] * rsqrtf(v1[oc] + 1e-5f);
      sh[u] = (b1[oc] - m1[oc]) * sc[u] + be1[oc];
    }
#pragma unroll
    for (int i = 0; i < 4; ++i) {
      int px0 = (wm + 2 * i) * 16 + lq * 4;
#pragma unroll
      for (int u = 0; u < 2; ++u) {
        int oc = wn * 32 + u * 16 + lm;
#pragma unroll
        for (int r = 0; r < 4; ++r) {
          int px = px0 + r;
          if (px < 100) {
            int hr = px / 10, hc = px - hr * 10;
            int gy = y0 - 1 + hr, gx = x0 - 1 + hc;
            bool valid = ((unsigned)gy < 64u) && ((unsigned)gx < 64u);
            float val = valid ? fast_tanh(acc[i][u][r] * sc[u] + sh[u]) : 0.f;
            hls[px * 72 + oc] = f2bf(val);
          }
        }
      }
    }
  }
  __syncthreads();

  // ---- phase 2: bc = tanh(bn2(conv2(h))), M=64, N=96, K=576 ----
  int hbase[2];
#pragma unroll
  for (int s = 0; s < 2; ++s) {
    int opx = (wm + 2 * s) * 16 + lm;
    int yl = opx >> 3, xl = opx & 7;
    hbase[s] = (yl * 10 + xl) * 72 + lq * 8;
  }
  floatx4 acc2[2][3];
#pragma unroll
  for (int s = 0; s < 2; ++s)
#pragma unroll
    for (int u = 0; u < 3; ++u) acc2[s][u] = floatx4{0.f, 0.f, 0.f, 0.f};

#pragma unroll
  for (int step = 0; step < 18; ++step) {
    const int off = step >> 1, kc = step & 1;
    const int di = off / 3, dj = off % 3;
    short8 b[3];
#pragma unroll
    for (int u = 0; u < 3; ++u)
      b[u] = *(const short8*)&w2swz[(off * 768 + kc * 384 + wn * 192 + u * 64 +
                                     lane) * 8];
#pragma unroll
    for (int s = 0; s < 2; ++s) {
      short8 a = *(const short8*)&hls[hbase[s] + (di * 10 + dj) * 72 + kc * 32];
      acc2[s][0] = MFMA16(a, b[0], acc2[s][0]);
      acc2[s][1] = MFMA16(a, b[1], acc2[s][1]);
      acc2[s][2] = MFMA16(a, b[2], acc2[s][2]);
    }
  }
  {
    float sc[3], sh[3];
#pragma unroll
    for (int u = 0; u < 3; ++u) {
      int oc = wn * 48 + u * 16 + lm;
      sc[u] = g2[oc] * rsqrtf(v2[oc] + 1e-5f);
      sh[u] = (b2[oc] - m2[oc]) * sc[u] + be2[oc];
    }
    unsigned short* bcn = bcg + (size_t)n * 4096 * 96;
#pragma unroll
    for (int s = 0; s < 2; ++s) {
      int opx0 = (wm + 2 * s) * 16 + lq * 4;
#pragma unroll
      for (int u = 0; u < 3; ++u) {
        int oc = wn * 48 + u * 16 + lm;
#pragma unroll
        for (int r = 0; r < 4; ++r) {
          int opx = opx0 + r;
          int y = y0 + (opx >> 3), xx = x0 + (opx & 7);
          bcn[((size_t)y * 64 + xx) * 96 + oc] =
              f2bf(fast_tanh(acc2[s][u][r] * sc[u] + sh[u]));
        }
      }
    }
  }
}

// ---------------------------------------------------------------------------
// adconv v11: SCHED_BARRIER-ENFORCED PIPELINE.
// R7 post-mortem: VGPR stayed 100 (gate <160) -> the asm "memory" fence did
// NOT hold Bf across build: MFMAs are register-only ops and can hoist across
// a memory clobber (skill rule #18's failure mode); the compiler restored
// load->wait->MFMA. v11 pins the schedule with sched_barrier(0) (NOTHING
// crosses, either direction):
//   [16 Bf loads + 2 Af ds_reads] | SB | [build ~330cyc VALU] | SB | [MFMA]
// -> the vmcnt wait for Bf lands after build; ~200cyc L2 latency hidden.
// Register peak at build ~205 (<256 cap at (256,2)); 2 waves/SIMD by design
// (ILP instead of TLP for this stall).
// Gates: VGPR 180-220 (fence worked); WRITE_SIZE 32.8MB (no spill).
// If VGPR high AND dur flat -> latency theory dead; pivot to global_load_lds
// B-staging (zero-VGPR prefetch).
// ---------------------------------------------------------------------------
__global__ __launch_bounds__(256, 2) void adconv_final(
    const unsigned short* __restrict__ xb, const unsigned short* __restrict__ bc,
    const float* __restrict__ bases, const unsigned short* __restrict__ coefswz,
    float* __restrict__ out) {
  __shared__ float xs[100 * 68];           // [(prow)*10 + qcol][c] fp32, 27.2 KB
  __shared__ unsigned short As[4 * 1024];  // per-wave [16px][64K] bf16, 8 KB

  const int t = threadIdx.x;
  const int tile = blockIdx.x, n = blockIdx.y;
  const int q0 = (tile & 7) * 8, p0 = (tile >> 3) * 8;

  float bs[54];
#pragma unroll
  for (int i = 0; i < 54; ++i) bs[i] = bases[i];

  // stage xs[pos][c] in fp32: rows p0-1..p0+8 (10), cols q0-1..q0+8 (10)
  const unsigned short* xbn = xb + (size_t)n * 4096 * 64;
#pragma unroll
  for (int it = 0; it < 4; ++it) {
    int idx = it * 256 + t;  // 800 total (100 pos x 8 bf16-uint4 units)
    if (idx < 800) {
      int pos = idx >> 3, u4 = idx & 7;
      int row = pos / 10, col = pos - row * 10;
      int gp = p0 - 1 + row, gq = q0 - 1 + col;
      uint4 v = {0u, 0u, 0u, 0u};
      if ((unsigned)gp < 64u && (unsigned)gq < 64u)
        v = *(const uint4*)&xbn[((size_t)gp * 64 + gq) * 64 + u4 * 8];
      float* d = &xs[pos * 68 + u4 * 8];
      *(float4*)d = make_float4(bflo(v.x), bfhi(v.x), bflo(v.y), bfhi(v.y));
      *(float4*)(d + 4) =
          make_float4(bflo(v.z), bfhi(v.z), bflo(v.w), bfhi(v.w));
    }
  }

  const int lane = t & 63, w = t >> 6;
  const int lm = lane & 15, lq = lane >> 4;

  // builder role: 4 threads/px, wave-aligned (wave w builds px w*16..+15)
  const int pxl_b = lane >> 2, fh4 = lane & 3;  // local px, f-quarter
  const int px_b = w * 16 + pxl_b;
  const int qx_b = px_b >> 3, py_b = px_b & 7;

  // atoms[k][j] for f = fh4*4 + j (j<4), f32 (36 VGPRs)
  float atf[9][4];
  {
    const unsigned short* bp =
        bc + ((size_t)n * 4096 + (q0 + qx_b) * 64 + (p0 + py_b)) * 96 + fh4 * 24;
    float bcv[24];
#pragma unroll
    for (int m = 0; m < 3; ++m) {
      uint4 v = *(const uint4*)(bp + m * 8);
      unsigned int uu[4] = {v.x, v.y, v.z, v.w};
#pragma unroll
      for (int e = 0; e < 4; ++e) {
        bcv[m * 8 + e * 2] = bflo(uu[e]);
        bcv[m * 8 + e * 2 + 1] = bfhi(uu[e]);
      }
    }
#pragma unroll
    for (int j = 0; j < 4; ++j)
#pragma unroll
      for (int k = 0; k < 9; ++k) {
        float s0 = 0.f;
#pragma unroll
        for (int tt = 0; tt < 6; ++tt)
          s0 = fmaf(bcv[j * 6 + tt], bs[tt * 9 + k], s0);
        atf[k][j] = s0;
      }
  }

  int pa[9];
#pragma unroll
  for (int i = 0; i < 3; ++i)
#pragma unroll
    for (int j = 0; j < 3; ++j)
      pa[i * 3 + j] = ((py_b + i) * 10 + qx_b + j) * 68;

  floatx4 acc[2][4];  // [wj][u]: full N=128 per wave
#pragma unroll
  for (int wj = 0; wj < 2; ++wj)
#pragma unroll
    for (int u = 0; u < 4; ++u) acc[wj][u] = floatx4{0.f, 0.f, 0.f, 0.f};

  unsigned short* Asw = &As[w * 1024];  // wave-private single buffer

  float4 qv[9];
  auto qload = [&](int rd) {
    const int coff = rd * 4;
#pragma unroll
    for (int p = 0; p < 9; ++p) qv[p] = *(const float4*)&xs[pa[p] + coff];
  };
  // build K-chunk (4 c, 4 f -> 16 K-elems per builder) into wave-private buf.
  auto build = [&]() {
    float a[4][4];
    {  // p = 0: mul (no zero-init pass)
#pragma unroll
      for (int j = 0; j < 4; ++j) {
        float av = atf[0][j];
        a[0][j] = qv[0].x * av;
        a[1][j] = qv[0].y * av;
        a[2][j] = qv[0].z * av;
        a[3][j] = qv[0].w * av;
      }
    }
#pragma unroll
    for (int p = 1; p < 9; ++p) {
#pragma unroll
      for (int j = 0; j < 4; ++j) {
        float av = atf[p][j];
        a[0][j] = fmaf(qv[p].x, av, a[0][j]);
        a[1][j] = fmaf(qv[p].y, av, a[1][j]);
        a[2][j] = fmaf(qv[p].z, av, a[2][j]);
        a[3][j] = fmaf(qv[p].w, av, a[3][j]);
      }
    }
#pragma unroll
    for (int cc = 0; cc < 4; ++cc) {
      int g = (cc * 4 + fh4) ^ ((pxl_b & 7) << 1);
      uint2 val;
      val.x = cvtpk(a[cc][0], a[cc][1]);
      val.y = cvtpk(a[cc][2], a[cc][3]);
      *(uint2*)&Asw[pxl_b * 64 + g * 4] = val;
    }
  };

  __syncthreads();  // xs staged (the only block-wide barrier)
  qload(0);
  build();

  for (int rd = 0; rd < 16; ++rd) {
    // 1) batch-issue ALL 16 B-frag loads + the 2 A-frag ds_reads.
    short8 Bf[2][2][4];
#pragma unroll
    for (int kc = 0; kc < 2; ++kc)
#pragma unroll
      for (int wj = 0; wj < 2; ++wj)
#pragma unroll
        for (int u = 0; u < 4; ++u) {
          int frag = ((rd * 2 + kc) * 2 + wj) * 4 + u;
          Bf[kc][wj][u] =
              *(const short8*)(coefswz + ((size_t)frag * 64 + lane) * 8);
        }
    short8 Af[2];
#pragma unroll
    for (int kc = 0; kc < 2; ++kc) {
      int u16 = (kc * 4 + lq) ^ (lm & 7);
      Af[kc] = *(const short8*)&Asw[lm * 64 + u16 * 8];
    }
    // HARD scheduler fence: nothing crosses (register ops included) -> the
    // loads above cannot sink, and build below cannot hoist.
    __builtin_amdgcn_sched_barrier(0);
    // 2) next-chunk build: ~330 VALU cycles hiding the B-load L2 latency.
    //    (Af ds_read precedes build's aliasing ds_write in program order;
    //    per-wave DS is in-order -> WAR-safe without a barrier.)
    if (rd < 15) {
      qload(rd + 1);
      build();
    }
    // HARD fence: MFMAs below cannot hoist above build -> their vmcnt wait
    // lands here, AFTER the latency blanket.
    __builtin_amdgcn_sched_barrier(0);
    // 3) consume: 16 MFMAs, operands all resident
    __builtin_amdgcn_s_setprio(1);
#pragma unroll
    for (int kc = 0; kc < 2; ++kc)
#pragma unroll
      for (int wj = 0; wj < 2; ++wj)
#pragma unroll
        for (int u = 0; u < 4; ++u)
          acc[wj][u] = MFMA16(Af[kc], Bf[kc][wj][u], acc[wj][u]);
    __builtin_amdgcn_s_setprio(0);
  }

  // epilogue: direct float4 stores (C/D reg-run contiguous along p)
  float* outn = out + (size_t)n * 128 * 4096;
#pragma unroll
  for (int wj = 0; wj < 2; ++wj)
#pragma unroll
    for (int u = 0; u < 4; ++u) {
      int oc = wj * 64 + u * 16 + lm;
      int gpx = w * 16 + lq * 4;  // tile-local px of acc run
      int qx = gpx >> 3, py0 = gpx & 7;
      *(float4*)&outn[((size_t)oc * 64 + q0 + qx) * 64 + p0 + py0] =
          make_float4(acc[wj][u][0], acc[wj][u][1], acc[wj][u][2],
                      acc[wj][u][3]);
    }
}

// ---------------------------------------------------------------------------
extern "C" void kernel_launch(void* const* d_in, const int* in_sizes, int n_in,
                              void* d_out, int out_size, void* d_ws,
                              size_t ws_size, hipStream_t stream) {
  const float* x = (const float*)d_in[0];
  const float* conv1_w = (const float*)d_in[1];
  const float* conv1_b = (const float*)d_in[2];
  const float* bn1_g = (const float*)d_in[3];
  const float* bn1_b = (const float*)d_in[4];
  const float* bn1_m = (const float*)d_in[5];
  const float* bn1_v = (const float*)d_in[6];
  const float* conv2_w = (const float*)d_in[7];
  const float* conv2_b = (const float*)d_in[8];
  const float* bn2_g = (const float*)d_in[9];
  const float* bn2_b = (const float*)d_in[10];
  const float* bn2_m = (const float*)d_in[11];
  const float* bn2_v = (const float*)d_in[12];
  const float* bases = (const float*)d_in[13];
  const float* coef = (const float*)d_in[14];
  float* out = (float*)d_out;

  char* ws = (char*)d_ws;
  unsigned short* xbuf = (unsigned short*)(ws);             // 8,388,608 B
  unsigned short* bcb = (unsigned short*)(ws + 8388608);    // 12,582,912 B
  unsigned short* w1swz = (unsigned short*)(ws + 20971520); // 73,728 B
  unsigned short* w2swz = (unsigned short*)(ws + 21045248); // 110,592 B
  unsigned short* coefswz = (unsigned short*)(ws + 21155840); // 262,144 B

  prep_all<<<dim3(96, NBATCH), 256, 0, stream>>>(x, xbuf, conv1_w, conv2_w,
                                                 coef, w1swz, w2swz, coefswz);
  fused_conv<<<dim3(64, NBATCH), 256, 0, stream>>>(
      xbuf, w1swz, w2swz, conv1_b, bn1_g, bn1_b, bn1_m, bn1_v, conv2_b, bn2_g,
      bn2_b, bn2_m, bn2_v, bcb);
  adconv_final<<<dim3(64, NBATCH), 256, 0, stream>>>(xbuf, bcb, bases, coefswz,
                                                     out);
}

// Round 9
// 162.305 us; speedup vs baseline: 1.0505x; 1.0181x over previous
//
#include <hip/hip_runtime.h>
#include <math.h>
#include <string.h>

#define NBATCH 16

typedef __attribute__((ext_vector_type(8))) short short8;
typedef __attribute__((ext_vector_type(4))) float floatx4;
#define MFMA16(a, b, c) __builtin_amdgcn_mfma_f32_16x16x32_bf16(a, b, c, 0, 0, 0)

// forced-resident global load: asm volatile cannot be sunk by ANY compiler
// pass; output regs stay live from issue to use. Waitcnt is MANUAL (the
// compiler cannot see inside asm) -> explicit s_waitcnt before consumption.
#define GLOAD(dst, ptr, offlit)                                   \
  asm volatile("global_load_dwordx4 %0, %1, off offset:" offlit   \
               : "=&v"(dst)                                       \
               : "v"(ptr)                                         \
               : "memory")

// hardware RNE bf16 conversion (1 VALU op per pair vs ~10 for manual RNE)
__device__ __forceinline__ unsigned int cvtpk(float a, float b) {
  unsigned int r;
  asm("v_cvt_pk_bf16_f32 %0, %1, %2" : "=v"(r) : "v"(a), "v"(b));
  return r;
}
__device__ __forceinline__ unsigned short f2bf(float f) {
  return (unsigned short)(cvtpk(f, 0.f) & 0xffffu);
}
__device__ __forceinline__ unsigned int packbf2(float a, float b) {
  return cvtpk(a, b);
}
__device__ __forceinline__ float bflo(unsigned int u) {
  return __uint_as_float(u << 16);
}
__device__ __forceinline__ float bfhi(unsigned int u) {
  return __uint_as_float(u & 0xffff0000u);
}
__device__ __forceinline__ float fast_tanh(float x) {
  float e = __expf(2.f * x);
  return 1.f - 2.f / (e + 1.f);
}

// ---------------------------------------------------------------------------
// prep_all: merged xb_prep (blockIdx.x < 64) + prep_weights (blockIdx.x >= 64)
// -> one launch instead of two. Branch is block-uniform.
// ---------------------------------------------------------------------------
__global__ __launch_bounds__(256) void prep_all(
    const float* __restrict__ x, unsigned short* __restrict__ xb,
    const float* __restrict__ w1, const float* __restrict__ w2,
    const float* __restrict__ coef, unsigned short* __restrict__ w1swz,
    unsigned short* __restrict__ w2swz, unsigned short* __restrict__ coefswz) {
  __shared__ float tile[64][65];
  const int t = threadIdx.x;
  if (blockIdx.x < 64) {
    const int y = blockIdx.x, n = blockIdx.y;
    const float* xn = x + (size_t)n * 64 * 4096 + y * 64;
#pragma unroll
    for (int it = 0; it < 16; ++it) {
      int idx = it * 256 + t;
      int c = idx >> 6, xx = idx & 63;
      tile[c][xx] = xn[c * 4096 + xx];
    }
    __syncthreads();
    const int xx = t >> 2, cq = t & 3;
    unsigned short* dst = xb + ((size_t)n * 4096 + y * 64 + xx) * 64;
#pragma unroll
    for (int jj = 0; jj < 2; ++jj) {
      int ch0 = cq * 16 + jj * 8;
      unsigned int p[4];
#pragma unroll
      for (int e = 0; e < 4; ++e)
        p[e] = packbf2(tile[ch0 + e * 2][xx], tile[ch0 + e * 2 + 1][xx]);
      *(uint4*)&dst[ch0] = make_uint4(p[0], p[1], p[2], p[3]);
    }
    return;
  }
  // weights part: reproduce old 512-block x 256-thread index space
  int i = ((blockIdx.x - 64) * NBATCH + blockIdx.y) * 256 + t;
  if (i < 131072) {
    int j = i & 7, f = i >> 3;
    int lane = f & 63;
    int u = (f >> 6) & 3;
    int wj = (f >> 8) & 1;
    int kc = (f >> 9) & 1;
    int rd = f >> 10;
    int lm = lane & 15, lq = lane >> 4;
    int oc = wj * 64 + u * 16 + lm;
    int k = rd * 64 + kc * 32 + lq * 8 + j;
    coefswz[i] = f2bf(coef[oc * 1024 + k]);
  }
  if (i < 36864) {
    int j = i & 7, f = i >> 3;
    int lane = f & 63;
    int u = (f >> 6) & 1;
    int wn = (f >> 7) & 1;
    int kc = (f >> 8) & 1;
    int off = f >> 9;
    int lm = lane & 15, lq = lane >> 4;
    int oc = wn * 32 + u * 16 + lm;
    int ic = kc * 32 + lq * 8 + j;
    w1swz[i] = f2bf(w1[(oc * 64 + ic) * 9 + off]);
  }
  if (i < 55296) {
    int j = i & 7, f = i >> 3;
    int lane = f & 63;
    int rem = f >> 6;
    int u = rem % 3;
    int rem2 = rem / 3;
    int wn = rem2 & 1;
    int kc = (rem2 >> 1) & 1;
    int off = rem2 >> 2;
    int lm = lane & 15, lq = lane >> 4;
    int oc = wn * 48 + u * 16 + lm;
    int ic = kc * 32 + lq * 8 + j;
    w2swz[i] = f2bf(w2[(oc * 64 + ic) * 9 + off]);
  }
}

// ---------------------------------------------------------------------------
// Fused conv1+BN+tanh -> h (LDS) -> conv2+BN+tanh -> bc (global NHWC bf16)
// 8x8 bc tile, grid (64, 16) = 1024 blocks (4/CU). LDS 39.2 KB.
// ---------------------------------------------------------------------------
__global__ __launch_bounds__(256) void fused_conv(
    const unsigned short* __restrict__ xb, const unsigned short* __restrict__ w1swz,
    const unsigned short* __restrict__ w2swz, const float* __restrict__ b1,
    const float* __restrict__ g1, const float* __restrict__ be1,
    const float* __restrict__ m1, const float* __restrict__ v1,
    const float* __restrict__ b2, const float* __restrict__ g2,
    const float* __restrict__ be2, const float* __restrict__ m2,
    const float* __restrict__ v2, unsigned short* __restrict__ bcg) {
  __shared__ unsigned short xls[144 * 72];  // [(xr*12+xc)][ic]
  __shared__ unsigned short hls[128 * 72];  // [hr*10+hc][oc], 100 used

  const int t = threadIdx.x;
  const int tile = blockIdx.x, n = blockIdx.y;
  const int x0 = (tile & 7) * 8, y0 = (tile >> 3) * 8;

  // stage x: rows y0-2..y0+9, cols x0-2..x0+9
  const unsigned short* xbn = xb + (size_t)n * 4096 * 64;
#pragma unroll
  for (int it = 0; it < 5; ++it) {
    int idx = it * 256 + t;  // 1152 total
    if (idx < 1152) {
      int pos = idx >> 3, u4 = idx & 7;
      int xr = pos / 12, xc = pos - xr * 12;
      int gy = y0 - 2 + xr, gx = x0 - 2 + xc;
      uint4 v = {0u, 0u, 0u, 0u};
      if ((unsigned)gy < 64u && (unsigned)gx < 64u)
        v = *(const uint4*)&xbn[((size_t)gy * 64 + gx) * 64 + u4 * 8];
      *(uint4*)&xls[pos * 72 + u4 * 8] = v;
    }
  }
  __syncthreads();

  const int lane = t & 63, w = t >> 6;
  const int wm = w & 1, wn = w >> 1;
  const int lm = lane & 15, lq = lane >> 4;

  // ---- phase 1: h = tanh(bn1(conv1(x))), M=128 (100 used), N=64, K=576 ----
  int abase[4];
#pragma unroll
  for (int i = 0; i < 4; ++i) {
    int px = (wm + 2 * i) * 16 + lm;
    if (px > 99) px = 99;
    int hr = px / 10, hc = px - hr * 10;
    abase[i] = (hr * 12 + hc) * 72 + lq * 8;
  }
  floatx4 acc[4][2];
#pragma unroll
  for (int i = 0; i < 4; ++i)
#pragma unroll
    for (int u = 0; u < 2; ++u) acc[i][u] = floatx4{0.f, 0.f, 0.f, 0.f};

#pragma unroll
  for (int step = 0; step < 18; ++step) {
    const int off = step >> 1, kc = step & 1;
    const int di = off / 3, dj = off % 3;
    short8 b[2];
#pragma unroll
    for (int u = 0; u < 2; ++u)
      b[u] = *(const short8*)&w1swz[(off * 512 + kc * 256 + wn * 128 + u * 64 +
                                     lane) * 8];
#pragma unroll
    for (int i = 0; i < 4; ++i) {
      short8 a = *(const short8*)&xls[abase[i] + (di * 12 + dj) * 72 + kc * 32];
      acc[i][0] = MFMA16(a, b[0], acc[i][0]);
      acc[i][1] = MFMA16(a, b[1], acc[i][1]);
    }
  }
  {
    float sc[2], sh[2];
#pragma unroll
    for (int u = 0; u < 2; ++u) {
      int oc = wn * 32 + u * 16 + lm;
      sc[u] = g1[oc] * rsqrtf(v1[oc] + 1e-5f);
      sh[u] = (b1[oc] - m1[oc]) * sc[u] + be1[oc];
    }
#pragma unroll
    for (int i = 0; i < 4; ++i) {
      int px0 = (wm + 2 * i) * 16 + lq * 4;
#pragma unroll
      for (int u = 0; u < 2; ++u) {
        int oc = wn * 32 + u * 16 + lm;
#pragma unroll
        for (int r = 0; r < 4; ++r) {
          int px = px0 + r;
          if (px < 100) {
            int hr = px / 10, hc = px - hr * 10;
            int gy = y0 - 1 + hr, gx = x0 - 1 + hc;
            bool valid = ((unsigned)gy < 64u) && ((unsigned)gx < 64u);
            float val = valid ? fast_tanh(acc[i][u][r] * sc[u] + sh[u]) : 0.f;
            hls[px * 72 + oc] = f2bf(val);
          }
        }
      }
    }
  }
  __syncthreads();

  // ---- phase 2: bc = tanh(bn2(conv2(h))), M=64, N=96, K=576 ----
  int hbase[2];
#pragma unroll
  for (int s = 0; s < 2; ++s) {
    int opx = (wm + 2 * s) * 16 + lm;
    int yl = opx >> 3, xl = opx & 7;
    hbase[s] = (yl * 10 + xl) * 72 + lq * 8;
  }
  floatx4 acc2[2][3];
#pragma unroll
  for (int s = 0; s < 2; ++s)
#pragma unroll
    for (int u = 0; u < 3; ++u) acc2[s][u] = floatx4{0.f, 0.f, 0.f, 0.f};

#pragma unroll
  for (int step = 0; step < 18; ++step) {
    const int off = step >> 1, kc = step & 1;
    const int di = off / 3, dj = off % 3;
    short8 b[3];
#pragma unroll
    for (int u = 0; u < 3; ++u)
      b[u] = *(const short8*)&w2swz[(off * 768 + kc * 384 + wn * 192 + u * 64 +
                                     lane) * 8];
#pragma unroll
    for (int s = 0; s < 2; ++s) {
      short8 a = *(const short8*)&hls[hbase[s] + (di * 10 + dj) * 72 + kc * 32];
      acc2[s][0] = MFMA16(a, b[0], acc2[s][0]);
      acc2[s][1] = MFMA16(a, b[1], acc2[s][1]);
      acc2[s][2] = MFMA16(a, b[2], acc2[s][2]);
    }
  }
  {
    float sc[3], sh[3];
#pragma unroll
    for (int u = 0; u < 3; ++u) {
      int oc = wn * 48 + u * 16 + lm;
      sc[u] = g2[oc] * rsqrtf(v2[oc] + 1e-5f);
      sh[u] = (b2[oc] - m2[oc]) * sc[u] + be2[oc];
    }
    unsigned short* bcn = bcg + (size_t)n * 4096 * 96;
#pragma unroll
    for (int s = 0; s < 2; ++s) {
      int opx0 = (wm + 2 * s) * 16 + lq * 4;
#pragma unroll
      for (int u = 0; u < 3; ++u) {
        int oc = wn * 48 + u * 16 + lm;
#pragma unroll
        for (int r = 0; r < 4; ++r) {
          int opx = opx0 + r;
          int y = y0 + (opx >> 3), xx = x0 + (opx & 7);
          bcn[((size_t)y * 64 + xx) * 96 + oc] =
              f2bf(fast_tanh(acc2[s][u][r] * sc[u] + sh[u]));
        }
      }
    }
  }
}

// ---------------------------------------------------------------------------
// adconv v12: ASM-FORCED B-PREFETCH.
// R6-R8 post-mortems: plain-load batch + "memory" fence + sched_barrier(0)
// all failed to hold Bf resident (VGPR stayed ~100) -- regular loads get
// sunk to uses by IR/MIR passes the sched_barrier doesn't constrain. v12
// issues the 16 B-frag loads as asm volatile global_load_dwordx4: NO pass
// can sink/delete them; output regs (64 VGPR) are live by construction.
// The compiler cannot see a load inside asm, so the wait is MANUAL:
//   [16 asm loads + 2 Af ds_reads] | SB | [build ~330cyc VALU blanket]
//   | s_waitcnt vmcnt(0) + SB |  [16 MFMA]   (rule-#18 fence pair)
// Gates: VGPR 190-240 (by construction); WRITE_SIZE 32.77MB + absmax
// 0.09375 (no spill -- spilling an un-waited asm output would corrupt).
// If dur stays ~52 with VGPR ~200: B-latency theory REFUTED -> pivot to
// fused_conv (the other ~50us of the pipeline, never yet in top-5).
// ---------------------------------------------------------------------------
__global__ __launch_bounds__(256, 2) void adconv_final(
    const unsigned short* __restrict__ xb, const unsigned short* __restrict__ bc,
    const float* __restrict__ bases, const unsigned short* __restrict__ coefswz,
    float* __restrict__ out) {
  __shared__ float xs[100 * 68];           // [(prow)*10 + qcol][c] fp32, 27.2 KB
  __shared__ unsigned short As[4 * 1024];  // per-wave [16px][64K] bf16, 8 KB

  const int t = threadIdx.x;
  const int tile = blockIdx.x, n = blockIdx.y;
  const int q0 = (tile & 7) * 8, p0 = (tile >> 3) * 8;

  float bs[54];
#pragma unroll
  for (int i = 0; i < 54; ++i) bs[i] = bases[i];

  // stage xs[pos][c] in fp32: rows p0-1..p0+8 (10), cols q0-1..q0+8 (10)
  const unsigned short* xbn = xb + (size_t)n * 4096 * 64;
#pragma unroll
  for (int it = 0; it < 4; ++it) {
    int idx = it * 256 + t;  // 800 total (100 pos x 8 bf16-uint4 units)
    if (idx < 800) {
      int pos = idx >> 3, u4 = idx & 7;
      int row = pos / 10, col = pos - row * 10;
      int gp = p0 - 1 + row, gq = q0 - 1 + col;
      uint4 v = {0u, 0u, 0u, 0u};
      if ((unsigned)gp < 64u && (unsigned)gq < 64u)
        v = *(const uint4*)&xbn[((size_t)gp * 64 + gq) * 64 + u4 * 8];
      float* d = &xs[pos * 68 + u4 * 8];
      *(float4*)d = make_float4(bflo(v.x), bfhi(v.x), bflo(v.y), bfhi(v.y));
      *(float4*)(d + 4) =
          make_float4(bflo(v.z), bfhi(v.z), bflo(v.w), bfhi(v.w));
    }
  }

  const int lane = t & 63, w = t >> 6;
  const int lm = lane & 15, lq = lane >> 4;

  // builder role: 4 threads/px, wave-aligned (wave w builds px w*16..+15)
  const int pxl_b = lane >> 2, fh4 = lane & 3;  // local px, f-quarter
  const int px_b = w * 16 + pxl_b;
  const int qx_b = px_b >> 3, py_b = px_b & 7;

  // atoms[k][j] for f = fh4*4 + j (j<4), f32 (36 VGPRs)
  float atf[9][4];
  {
    const unsigned short* bp =
        bc + ((size_t)n * 4096 + (q0 + qx_b) * 64 + (p0 + py_b)) * 96 + fh4 * 24;
    float bcv[24];
#pragma unroll
    for (int m = 0; m < 3; ++m) {
      uint4 v = *(const uint4*)(bp + m * 8);
      unsigned int uu[4] = {v.x, v.y, v.z, v.w};
#pragma unroll
      for (int e = 0; e < 4; ++e) {
        bcv[m * 8 + e * 2] = bflo(uu[e]);
        bcv[m * 8 + e * 2 + 1] = bfhi(uu[e]);
      }
    }
#pragma unroll
    for (int j = 0; j < 4; ++j)
#pragma unroll
      for (int k = 0; k < 9; ++k) {
        float s0 = 0.f;
#pragma unroll
        for (int tt = 0; tt < 6; ++tt)
          s0 = fmaf(bcv[j * 6 + tt], bs[tt * 9 + k], s0);
        atf[k][j] = s0;
      }
  }

  int pa[9];
#pragma unroll
  for (int i = 0; i < 3; ++i)
#pragma unroll
    for (int j = 0; j < 3; ++j)
      pa[i * 3 + j] = ((py_b + i) * 10 + qx_b + j) * 68;

  floatx4 acc[2][4];  // [wj][u]: full N=128 per wave
#pragma unroll
  for (int wj = 0; wj < 2; ++wj)
#pragma unroll
    for (int u = 0; u < 4; ++u) acc[wj][u] = floatx4{0.f, 0.f, 0.f, 0.f};

  unsigned short* Asw = &As[w * 1024];  // wave-private single buffer

  float4 qv[9];
  auto qload = [&](int rd) {
    const int coff = rd * 4;
#pragma unroll
    for (int p = 0; p < 9; ++p) qv[p] = *(const float4*)&xs[pa[p] + coff];
  };
  // build K-chunk (4 c, 4 f -> 16 K-elems per builder) into wave-private buf.
  auto build = [&]() {
    float a[4][4];
    {  // p = 0: mul (no zero-init pass)
#pragma unroll
      for (int j = 0; j < 4; ++j) {
        float av = atf[0][j];
        a[0][j] = qv[0].x * av;
        a[1][j] = qv[0].y * av;
        a[2][j] = qv[0].z * av;
        a[3][j] = qv[0].w * av;
      }
    }
#pragma unroll
    for (int p = 1; p < 9; ++p) {
#pragma unroll
      for (int j = 0; j < 4; ++j) {
        float av = atf[p][j];
        a[0][j] = fmaf(qv[p].x, av, a[0][j]);
        a[1][j] = fmaf(qv[p].y, av, a[1][j]);
        a[2][j] = fmaf(qv[p].z, av, a[2][j]);
        a[3][j] = fmaf(qv[p].w, av, a[3][j]);
      }
    }
#pragma unroll
    for (int cc = 0; cc < 4; ++cc) {
      int g = (cc * 4 + fh4) ^ ((pxl_b & 7) << 1);
      uint2 val;
      val.x = cvtpk(a[cc][0], a[cc][1]);
      val.y = cvtpk(a[cc][2], a[cc][3]);
      *(uint2*)&Asw[pxl_b * 64 + g * 4] = val;
    }
  };

  __syncthreads();  // xs staged (the only block-wide barrier)
  qload(0);
  build();

  for (int rd = 0; rd < 16; ++rd) {
    // 1) issue ALL 16 B-frag loads via asm (un-sinkable, regs live by
    //    construction). frag = rd*16 + kc*8 + wj*4 + u; byte addr =
    //    base + frag*1024 + lane*16.
    short8 Bf[2][2][4];
    {
      const unsigned short* b0 = coefswz + (size_t)rd * 8192 + lane * 8;
      const unsigned short* b1 = b0 + 2048;  // wj=1: +4096 B
      const unsigned short* b2 = b0 + 4096;  // kc=1: +8192 B
      const unsigned short* b3 = b0 + 6144;
      GLOAD(Bf[0][0][0], b0, "0");
      GLOAD(Bf[0][0][1], b0, "1024");
      GLOAD(Bf[0][0][2], b0, "2048");
      GLOAD(Bf[0][0][3], b0, "3072");
      GLOAD(Bf[0][1][0], b1, "0");
      GLOAD(Bf[0][1][1], b1, "1024");
      GLOAD(Bf[0][1][2], b1, "2048");
      GLOAD(Bf[0][1][3], b1, "3072");
      GLOAD(Bf[1][0][0], b2, "0");
      GLOAD(Bf[1][0][1], b2, "1024");
      GLOAD(Bf[1][0][2], b2, "2048");
      GLOAD(Bf[1][0][3], b2, "3072");
      GLOAD(Bf[1][1][0], b3, "0");
      GLOAD(Bf[1][1][1], b3, "1024");
      GLOAD(Bf[1][1][2], b3, "2048");
      GLOAD(Bf[1][1][3], b3, "3072");
    }
    // 2) A frags for rd (ds_read precedes build's aliasing ds_write in
    //    program order; per-wave DS is in-order -> WAR-safe)
    short8 Af[2];
#pragma unroll
    for (int kc = 0; kc < 2; ++kc) {
      int u16 = (kc * 4 + lq) ^ (lm & 7);
      Af[kc] = *(const short8*)&Asw[lm * 64 + u16 * 8];
    }
    __builtin_amdgcn_sched_barrier(0);
    // 3) next-chunk build: ~330 VALU cycles hiding the B-load latency
    if (rd < 15) {
      qload(rd + 1);
      build();
    }
    // 4) manual wait for the asm loads, fenced so MFMAs cannot hoist above
    //    it (rule #18), then consume.
    asm volatile("s_waitcnt vmcnt(0)" ::: "memory");
    __builtin_amdgcn_sched_barrier(0);
    __builtin_amdgcn_s_setprio(1);
#pragma unroll
    for (int kc = 0; kc < 2; ++kc)
#pragma unroll
      for (int wj = 0; wj < 2; ++wj)
#pragma unroll
        for (int u = 0; u < 4; ++u)
          acc[wj][u] = MFMA16(Af[kc], Bf[kc][wj][u], acc[wj][u]);
    __builtin_amdgcn_s_setprio(0);
  }

  // epilogue: direct float4 stores (C/D reg-run contiguous along p)
  float* outn = out + (size_t)n * 128 * 4096;
#pragma unroll
  for (int wj = 0; wj < 2; ++wj)
#pragma unroll
    for (int u = 0; u < 4; ++u) {
      int oc = wj * 64 + u * 16 + lm;
      int gpx = w * 16 + lq * 4;  // tile-local px of acc run
      int qx = gpx >> 3, py0 = gpx & 7;
      *(float4*)&outn[((size_t)oc * 64 + q0 + qx) * 64 + p0 + py0] =
          make_float4(acc[wj][u][0], acc[wj][u][1], acc[wj][u][2],
                      acc[wj][u][3]);
    }
}

// ---------------------------------------------------------------------------
extern "C" void kernel_launch(void* const* d_in, const int* in_sizes, int n_in,
                              void* d_out, int out_size, void* d_ws,
                              size_t ws_size, hipStream_t stream) {
  const float* x = (const float*)d_in[0];
  const float* conv1_w = (const float*)d_in[1];
  const float* conv1_b = (const float*)d_in[2];
  const float* bn1_g = (const float*)d_in[3];
  const float* bn1_b = (const float*)d_in[4];
  const float* bn1_m = (const float*)d_in[5];
  const float* bn1_v = (const float*)d_in[6];
  const float* conv2_w = (const float*)d_in[7];
  const float* conv2_b = (const float*)d_in[8];
  const float* bn2_g = (const float*)d_in[9];
  const float* bn2_b = (const float*)d_in[10];
  const float* bn2_m = (const float*)d_in[11];
  const float* bn2_v = (const float*)d_in[12];
  const float* bases = (const float*)d_in[13];
  const float* coef = (const float*)d_in[14];
  float* out = (float*)d_out;

  char* ws = (char*)d_ws;
  unsigned short* xbuf = (unsigned short*)(ws);             // 8,388,608 B
  unsigned short* bcb = (unsigned short*)(ws + 8388608);    // 12,582,912 B
  unsigned short* w1swz = (unsigned short*)(ws + 20971520); // 73,728 B
  unsigned short* w2swz = (unsigned short*)(ws + 21045248); // 110,592 B
  unsigned short* coefswz = (unsigned short*)(ws + 21155840); // 262,144 B

  prep_all<<<dim3(96, NBATCH), 256, 0, stream>>>(x, xbuf, conv1_w, conv2_w,
                                                 coef, w1swz, w2swz, coefswz);
  fused_conv<<<dim3(64, NBATCH), 256, 0, stream>>>(
      xbuf, w1swz, w2swz, conv1_b, bn1_g, bn1_b, bn1_m, bn1_v, conv2_b, bn2_g,
      bn2_b, bn2_m, bn2_v, bcb);
  adconv_final<<<dim3(64, NBATCH), 256, 0, stream>>>(xbuf, bcb, bases, coefswz,
                                                     out);
}